// Round 5
// baseline (187.758 us; speedup 1.0000x reference)
//
#include <hip/hip_runtime.h>
#include <math.h>

// Problem constants (from reference)
constexpr int B_ = 16, T_ = 256, D_ = 384, M_ = 2048, F_ = 256, NMEL_ = 80;
constexpr float PACE_ = 1.0f, MAXDUR_ = 75.0f;
constexpr int R_ = B_ * T_;  // 4096 total rows

typedef __attribute__((ext_vector_type(8))) short bf16x8;
typedef __attribute__((ext_vector_type(4))) float f32x4_;

static __device__ __forceinline__ unsigned short f2bf(float x) {
    union { float f; unsigned int u; } v; v.f = x;
    const unsigned int r = v.u + 0x7fffu + ((v.u >> 16) & 1u);  // RNE
    return (unsigned short)(r >> 16);
}
static __device__ __forceinline__ float bf2f(unsigned short h) {
    union { float f; unsigned int u; } v; v.u = ((unsigned int)h) << 16;
    return v.f;
}

// ---------------------------------------------------------------------------
// Weight repack device job: w[F_,CIN,3] fp32 -> bf16 16x16x32 B-frag order:
//   p[ ((k*(F_/16)+fn)*(CIN/32)+c)*512 + lane*8 + j ]
//     = w[f=fn*16+(lane&15)][d=c*32+(lane>>4)*8+j][k]
// ---------------------------------------------------------------------------
template <int CIN>
static __device__ void repack_job(int bx, const float* __restrict__ w,
                                  unsigned short* __restrict__ p)
{
    constexpr int NC = CIN / 32;
    const int gid = bx * 256 + threadIdx.x;   // over 3*F_*CIN/8
    const int lane = gid & 63;
    int rest = gid >> 6;
    const int c = rest % NC;  rest /= NC;
    const int fn = rest % (F_ / 16);
    const int k  = rest / (F_ / 16);
    const int f = fn * 16 + (lane & 15);
    const int d = c * 32 + (lane >> 4) * 8;
    uint4 o;
    unsigned short* op = (unsigned short*)&o;
#pragma unroll
    for (int j = 0; j < 8; j++)
        op[j] = f2bf(w[((size_t)f * CIN + d + j) * 3 + k]);
    ((uint4*)p)[gid] = o;
}

// ---------------------------------------------------------------------------
// prep mega-kernel: all input-only work in ONE dispatch.
//  job A: repack conv0 weights (dur, pitch)      2 x 144 blocks
//  job B: repack conv1 weights (dur, pitch)      2 x  96 blocks
//  job C: repack proj_w                               15 blocks
//  job D: encb = bf16(enc_out + pitch_emb_conv)     1536 blocks
//  job E: regulate_len (cumsum+searchsorted)          16 blocks
// ---------------------------------------------------------------------------
constexpr int NA_ = 144, NB_ = 96, NCB_ = 15, ND_ = R_ * D_ / 4 / 256, NE_ = B_;
constexpr int OFF_B = 2 * NA_;            // 288
constexpr int OFF_C = OFF_B + 2 * NB_;    // 480
constexpr int OFF_D = OFF_C + NCB_;       // 495
constexpr int OFF_E = OFF_D + ND_;        // 2031
constexpr int NPREP = OFF_E + NE_;        // 2047

__global__ __launch_bounds__(256) void prep_kernel(
    const float* __restrict__ dc0w, const float* __restrict__ pc0w,
    const float* __restrict__ dc1w, const float* __restrict__ pc1w,
    const float* __restrict__ projw,
    const float* __restrict__ enc_out, const float* __restrict__ pt,
    const float* __restrict__ we, const float* __restrict__ be,
    const int* __restrict__ dur,
    unsigned short* __restrict__ pw0d, unsigned short* __restrict__ pw0p,
    unsigned short* __restrict__ pw1d, unsigned short* __restrict__ pw1p,
    unsigned short* __restrict__ pwb, unsigned short* __restrict__ encb,
    int* __restrict__ idx_out, float* __restrict__ dec_mask)
{
    __shared__ int cums[T_];
    const int bx = blockIdx.x;

    if (bx < OFF_B) {                                   // job A
        if (bx < NA_) repack_job<D_>(bx, dc0w, pw0d);
        else          repack_job<D_>(bx - NA_, pc0w, pw0p);
    } else if (bx < OFF_C) {                            // job B
        const int b2 = bx - OFF_B;
        if (b2 < NB_) repack_job<F_>(b2, dc1w, pw1d);
        else          repack_job<F_>(b2 - NB_, pc1w, pw1p);
    } else if (bx < OFF_D) {                            // job C: proj repack
        const int gid = (bx - OFF_C) * 256 + threadIdx.x;  // over 3840
        const int lane = gid & 63;
        const int rest = gid >> 6;
        const int nt = rest % 5;
        const int c  = rest / 5;
        const int n = nt * 16 + (lane & 15);
        const int k = c * 32 + (lane >> 4) * 8;
        uint4 o;
        unsigned short* op = (unsigned short*)&o;
#pragma unroll
        for (int j = 0; j < 8; j++)
            op[j] = f2bf(projw[(size_t)n * D_ + k + j]);
        ((uint4*)pwb)[gid] = o;
    } else if (bx < OFF_E) {                            // job D: pitch add
        const int gid = (bx - OFF_D) * 256 + threadIdx.x;  // over R_*D_/4
        const int dq = gid % (D_ / 4);
        const int bt = gid / (D_ / 4);
        const int t = bt & 255, b = bt >> 8;
        const int d = dq * 4;
        const float4 e = ((const float4*)enc_out)[gid];
        const float p0 = (t > 0)   ? pt[b * T_ + t - 1] : 0.f;
        const float p1 = pt[b * T_ + t];
        const float p2 = (t < 255) ? pt[b * T_ + t + 1] : 0.f;
        const float* ev = (const float*)&e;
        ushort4 o;
        unsigned short* op = (unsigned short*)&o;
#pragma unroll
        for (int dd = 0; dd < 4; dd++) {
            float s = be[d + dd];
            s = fmaf(we[(d + dd) * 3 + 0], p0, s);
            s = fmaf(we[(d + dd) * 3 + 1], p1, s);
            s = fmaf(we[(d + dd) * 3 + 2], p2, s);
            op[dd] = f2bf(ev[dd] + s);
        }
        ((ushort4*)encb)[gid] = o;
    } else {                                            // job E: regulate
        const int b = bx - OFF_E, t = threadIdx.x;
        cums[t] = (int)rintf((float)dur[b * T_ + t] / PACE_);
        __syncthreads();
        for (int off = 1; off < T_; off <<= 1) {
            int v = cums[t];
            if (t >= off) v += cums[t - off];
            __syncthreads();
            cums[t] = v;
            __syncthreads();
        }
        const int dec_len = min(cums[T_ - 1], M_);
#pragma unroll
        for (int r = 0; r < M_ / T_; r++) {
            const int j = r * T_ + t;
            int lo = 0, hi = T_;
            while (lo < hi) {
                const int mid = (lo + hi) >> 1;
                if (cums[mid] <= j) lo = mid + 1; else hi = mid;
            }
            idx_out[b * M_ + j]  = min(lo, T_ - 1);
            dec_mask[b * M_ + j] = (j < dec_len) ? 1.f : 0.f;
        }
    }
}

// ---------------------------------------------------------------------------
// Fused Conv1d(K=3,SAME)+bias+ReLU+LayerNorm (+optional FC head) via MFMA.
// Block: 16 t-rows x ALL 256 f; 4 waves, wave w = 4 n-frags (f = w*64..+63).
// Grid (R_/16, 1, 2): z = predictor (dur/pitch).
// LDS overlay: x-tile (bf16, halo) -> h-tile (fp32) after MFMA completes.
// FC=true: LN output never hits global; FC dot via wave shuffle-reduce.
// ---------------------------------------------------------------------------
template <int CIN, bool FP32IN, bool FC>
__global__ __launch_bounds__(256) void convln_kernel(
    const void* __restrict__ in0, const void* __restrict__ in1,
    const float* __restrict__ mask,
    const unsigned short* __restrict__ pw0, const unsigned short* __restrict__ pw1,
    const float* __restrict__ bias0, const float* __restrict__ bias1,
    const float* __restrict__ g0, const float* __restrict__ nb0,
    const float* __restrict__ g1, const float* __restrict__ nb1,
    const float* __restrict__ fcw0, const float* __restrict__ fcw1,
    const float* __restrict__ fcb0, const float* __restrict__ fcb1,
    unsigned short* __restrict__ out0, unsigned short* __restrict__ out1,
    float* __restrict__ pred0, float* __restrict__ pred1,
    float* __restrict__ durpred)
{
    constexpr int LDX = CIN + 8;          // padded x row stride (bf16)
    constexpr int NC  = CIN / 32;
    constexpr int HSW = F_ + 4;           // padded h row stride (fp32)
    constexpr int SB1 = 18 * LDX * 2, SB2 = 16 * HSW * 4;
    __shared__ __align__(16) char smem[(SB1 > SB2) ? SB1 : SB2];
    __shared__ float mu_s[16], rs_s[16], red[4][16];
    unsigned short* xs = (unsigned short*)smem;
    float* hs = (float*)smem;

    const int z = blockIdx.z;
    const void* in = z ? in1 : in0;
    const unsigned short* pw = z ? pw1 : pw0;
    const float* bias = z ? bias1 : bias0;
    const float* g  = z ? g1 : g0;
    const float* nb = z ? nb1 : nb0;
    const int r0  = blockIdx.x * 16;      // 16-row tiles never cross a batch
    const int bb  = r0 >> 8;
    const int tl  = r0 & 255;
    const int tid = threadIdx.x;

    // ---- stage x rows tl-1 .. tl+16 (18 rows), zero outside batch ----
    if (FP32IN) {
        const float* x = (const float*)in;
        for (int i = tid; i < 18 * (CIN / 8); i += 256) {
            const int row = i / (CIN / 8);
            const int dd  = (i - row * (CIN / 8)) * 8;
            const int t   = tl - 1 + row;
            ushort4 o0 = {0, 0, 0, 0}, o1 = {0, 0, 0, 0};
            if (t >= 0 && t < 256) {
                const float m = mask[bb * 256 + t];
                const float* xr = x + (size_t)(bb * 256 + t) * CIN + dd;
                const float4 v0 = *(const float4*)xr;
                const float4 v1 = *(const float4*)(xr + 4);
                o0.x = f2bf(v0.x * m); o0.y = f2bf(v0.y * m);
                o0.z = f2bf(v0.z * m); o0.w = f2bf(v0.w * m);
                o1.x = f2bf(v1.x * m); o1.y = f2bf(v1.y * m);
                o1.z = f2bf(v1.z * m); o1.w = f2bf(v1.w * m);
            }
            *(ushort4*)(&xs[row * LDX + dd])     = o0;
            *(ushort4*)(&xs[row * LDX + dd + 4]) = o1;
        }
    } else {
        const unsigned short* x = (const unsigned short*)in;
        for (int i = tid; i < 18 * (CIN / 8); i += 256) {
            const int row = i / (CIN / 8);
            const int dd  = (i - row * (CIN / 8)) * 8;
            const int t   = tl - 1 + row;
            uint4 v = make_uint4(0, 0, 0, 0);
            if (t >= 0 && t < 256)
                v = *(const uint4*)(x + (size_t)(bb * 256 + t) * CIN + dd);
            *(uint4*)(&xs[row * LDX + dd]) = v;
        }
    }
    __syncthreads();

    const int w = tid >> 6, l = tid & 63;
    const int q = l >> 4, lm = l & 15;

    f32x4_ acc[4][3];
#pragma unroll
    for (int nf = 0; nf < 4; nf++)
#pragma unroll
        for (int k = 0; k < 3; k++)
#pragma unroll
            for (int i = 0; i < 4; i++) acc[nf][k][i] = 0.f;

    for (int c = 0; c < NC; c++) {
        bf16x8 a[3];
#pragma unroll
        for (int tap = 0; tap < 3; tap++)   // A row m=lm, halo offset tap
            a[tap] = *(const bf16x8*)(&xs[(lm + tap) * LDX + c * 32 + q * 8]);
#pragma unroll
        for (int tap = 0; tap < 3; tap++) {
#pragma unroll
            for (int nf = 0; nf < 4; nf++) {
                const bf16x8 b = *(const bf16x8*)(
                    pw + ((((size_t)tap * (F_ / 16) + w * 4 + nf) * NC + c) << 9) + l * 8);
                acc[nf][tap] = __builtin_amdgcn_mfma_f32_16x16x32_bf16(
                    a[tap], b, acc[nf][tap], 0, 0, 0);
            }
        }
    }

    // ---- h tile to LDS (overlays xs).  C/D: col=lane&15, row=q*4+reg ----
    __syncthreads();
#pragma unroll
    for (int nf = 0; nf < 4; nf++) {
        const int f = (w * 4 + nf) * 16 + lm;
        const float bs = bias[f];
#pragma unroll
        for (int r = 0; r < 4; r++) {
            const int m = q * 4 + r;
            const float v = acc[nf][0][r] + acc[nf][1][r] + acc[nf][2][r] + bs;
            hs[m * HSW + f] = fmaxf(v, 0.f);
        }
    }
    __syncthreads();

    // ---- LN stats: 16 threads per row ----
    {
        const int s = tid & 15, row = tid >> 4;
        float sm = 0.f, sq = 0.f;
#pragma unroll
        for (int i = 0; i < 16; i++) {
            const float v = hs[row * HSW + s + 16 * i];
            sm += v; sq += v * v;
        }
#pragma unroll
        for (int off = 8; off >= 1; off >>= 1) {
            sm += __shfl_xor(sm, off);
            sq += __shfl_xor(sq, off);
        }
        if (s == 0) {
            const float m = sm * (1.f / F_);
            mu_s[row] = m;
            rs_s[row] = rsqrtf(sq * (1.f / F_) - m * m + 1e-5f);
        }
    }
    __syncthreads();

    const float gf = g[tid], bf = nb[tid];
    if (!FC) {
        unsigned short* out = z ? out1 : out0;
#pragma unroll
        for (int m = 0; m < 16; m++) {
            const float v = (hs[m * HSW + tid] - mu_s[m]) * rs_s[m] * gf + bf;
            out[(size_t)(r0 + m) * F_ + tid] = f2bf(v);
        }
    } else {
        const float* fcw = z ? fcw1 : fcw0;
        const float wf = fcw[tid];
#pragma unroll
        for (int m = 0; m < 16; m++) {
            const float v = (hs[m * HSW + tid] - mu_s[m]) * rs_s[m] * gf + bf;
            float p = v * wf;
#pragma unroll
            for (int off = 32; off >= 1; off >>= 1) p += __shfl_xor(p, off);
            if (l == 0) red[w][m] = p;
        }
        __syncthreads();
        if (tid < 16) {
            const float* fcb = z ? fcb1 : fcb0;
            float* pred = z ? pred1 : pred0;
            const float s = red[0][tid] + red[1][tid] + red[2][tid] + red[3][tid];
            const float p = (s + fcb[0]) * mask[r0 + tid];
            pred[r0 + tid] = p;
            if (!z && durpred)
                durpred[r0 + tid] = fminf(fmaxf(expf(p) - 1.f, 0.f), MAXDUR_);
        }
    }
}

// ---------------------------------------------------------------------------
// mel gather-GEMM via MFMA 16x16x32 (validated round 4).
// ---------------------------------------------------------------------------
__global__ __launch_bounds__(256) void mel_mfma_kernel(
    const unsigned short* __restrict__ encb, const int* __restrict__ idx,
    const float* __restrict__ dmask, const unsigned short* __restrict__ pwb,
    const float* __restrict__ pb, float* __restrict__ mel)
{
    __shared__ int ids[64];
    const int b  = blockIdx.y;
    const int j0 = blockIdx.x * 64;
    const int tid = threadIdx.x;
    if (tid < 64) ids[tid] = idx[b * M_ + j0 + tid];
    __syncthreads();

    const int w = tid >> 6, l = tid & 63;
    const int q = l >> 4, lm = l & 15;
    const int row = ids[w * 16 + lm];
    const unsigned short* ap = encb + ((size_t)(b * 256 + row)) * D_ + q * 8;

    f32x4_ acc[5];
#pragma unroll
    for (int nt = 0; nt < 5; nt++)
#pragma unroll
        for (int i = 0; i < 4; i++) acc[nt][i] = 0.f;

    for (int c = 0; c < D_ / 32; c++) {
        const bf16x8 a = *(const bf16x8*)(ap + c * 32);
#pragma unroll
        for (int nt = 0; nt < 5; nt++) {
            const bf16x8 bv = *(const bf16x8*)(pwb + (((size_t)c * 5 + nt) << 9) + l * 8);
            acc[nt] = __builtin_amdgcn_mfma_f32_16x16x32_bf16(a, bv, acc[nt], 0, 0, 0);
        }
    }

    float msk[4];
#pragma unroll
    for (int r = 0; r < 4; r++)
        msk[r] = dmask[b * M_ + j0 + w * 16 + q * 4 + r];
#pragma unroll
    for (int nt = 0; nt < 5; nt++) {
        const int n = nt * 16 + lm;
        const float bb = pb[n];
#pragma unroll
        for (int r = 0; r < 4; r++) {
            const int j = j0 + w * 16 + q * 4 + r;
            mel[((size_t)b * M_ + j) * NMEL_ + n] = msk[r] * acc[nt][r] + bb;
        }
    }
}

// ---------------------------------------------------------------------------
extern "C" void kernel_launch(void* const* d_in, const int* in_sizes, int n_in,
                              void* d_out, int out_size, void* d_ws, size_t ws_size,
                              hipStream_t stream)
{
    const float* enc_out   = (const float*)d_in[0];
    const float* enc_mask  = (const float*)d_in[1];
    const float* pitch_tgt = (const float*)d_in[2];
    const int*   durations = (const int*)d_in[3];

    const float* dur_c0_w = (const float*)d_in[4];
    const float* dur_c0_b = (const float*)d_in[5];
    const float* dur_n0_g = (const float*)d_in[6];
    const float* dur_n0_b = (const float*)d_in[7];
    const float* dur_c1_w = (const float*)d_in[8];
    const float* dur_c1_b = (const float*)d_in[9];
    const float* dur_n1_g = (const float*)d_in[10];
    const float* dur_n1_b = (const float*)d_in[11];
    const float* dur_fc_w = (const float*)d_in[12];
    const float* dur_fc_b = (const float*)d_in[13];

    const float* pit_c0_w = (const float*)d_in[14];
    const float* pit_c0_b = (const float*)d_in[15];
    const float* pit_n0_g = (const float*)d_in[16];
    const float* pit_n0_b = (const float*)d_in[17];
    const float* pit_c1_w = (const float*)d_in[18];
    const float* pit_c1_b = (const float*)d_in[19];
    const float* pit_n1_g = (const float*)d_in[20];
    const float* pit_n1_b = (const float*)d_in[21];
    const float* pit_fc_w = (const float*)d_in[22];
    const float* pit_fc_b = (const float*)d_in[23];

    const float* pemb_w = (const float*)d_in[24];
    const float* pemb_b = (const float*)d_in[25];
    const float* proj_w = (const float*)d_in[26];
    const float* proj_b = (const float*)d_in[27];

    // Output slices (flat, in return order), all fp32.
    float* out       = (float*)d_out;
    float* mel_out   = out;                                   // [B,M,NMEL]
    float* dec_mask  = mel_out + (size_t)B_ * M_ * NMEL_;     // [B,M,1]
    float* dur_pred  = dec_mask + (size_t)B_ * M_;            // [B,T]
    float* log_dur   = dur_pred + (size_t)B_ * T_;            // [B,T]
    float* pitch_prd = log_dur + (size_t)B_ * T_;             // [B,T]

    // Workspace layout (~10 MiB)
    char* wp = (char*)d_ws;
    unsigned short* pw0d = (unsigned short*)wp; wp += (size_t)3 * F_ * D_ * 2;   // 590 KB
    unsigned short* pw0p = (unsigned short*)wp; wp += (size_t)3 * F_ * D_ * 2;
    unsigned short* pw1d = (unsigned short*)wp; wp += (size_t)3 * F_ * F_ * 2;   // 393 KB
    unsigned short* pw1p = (unsigned short*)wp; wp += (size_t)3 * F_ * F_ * 2;
    unsigned short* pwb  = (unsigned short*)wp; wp += (size_t)5 * 12 * 512 * 2;  // 61 KB
    unsigned short* encb = (unsigned short*)wp; wp += (size_t)R_ * D_ * 2;       // 3.15 MB
    unsigned short* hb_d = (unsigned short*)wp; wp += (size_t)R_ * F_ * 2;       // 2.10 MB
    unsigned short* hb_p = (unsigned short*)wp; wp += (size_t)R_ * F_ * 2;
    int*            idx  = (int*)wp;                                             // 131 KB

    const dim3 blk(256);

    // 1) all input-only prep in one dispatch
    prep_kernel<<<NPREP, blk, 0, stream>>>(
        dur_c0_w, pit_c0_w, dur_c1_w, pit_c1_w, proj_w,
        enc_out, pitch_tgt, pemb_w, pemb_b, durations,
        pw0d, pw0p, pw1d, pw1p, pwb, encb, idx, dec_mask);

    // 2) conv0 + LN (dur & pitch), fp32 input with mask folded
    convln_kernel<D_, true, false><<<dim3(R_ / 16, 1, 2), blk, 0, stream>>>(
        enc_out, enc_out, enc_mask, pw0d, pw0p, dur_c0_b, pit_c0_b,
        dur_n0_g, dur_n0_b, pit_n0_g, pit_n0_b,
        nullptr, nullptr, nullptr, nullptr,
        hb_d, hb_p, nullptr, nullptr, nullptr);

    // 3) conv1 + LN + FC head (dur & pitch); writes only [B,T] predictions
    convln_kernel<F_, false, true><<<dim3(R_ / 16, 1, 2), blk, 0, stream>>>(
        hb_d, hb_p, enc_mask, pw1d, pw1p, dur_c1_b, pit_c1_b,
        dur_n1_g, dur_n1_b, pit_n1_g, pit_n1_b,
        dur_fc_w, pit_fc_w, dur_fc_b, pit_fc_b,
        nullptr, nullptr, log_dur, pitch_prd, dur_pred);

    // 4) gather + projection to mel
    mel_mfma_kernel<<<dim3(M_ / 64, B_), blk, 0, stream>>>(
        encb, idx, dec_mask, pwb, proj_b, mel_out);
}